// Round 1
// baseline (273.358 us; speedup 1.0000x reference)
//
#include <hip/hip_runtime.h>
#include <math.h>

#define CCH 64
#define NVOX 4096
#define NB 2

// ---------------- Kernel A: fused QKV projection ----------------
// x: [B, C, N]; W*: [C, C] row-major (out, in); b*: [C]
// outputs qT, kT, vT: [B, N, C]
__global__ __launch_bounds__(256) void qkv_proj(
    const float* __restrict__ x,
    const float* __restrict__ Wq, const float* __restrict__ bq,
    const float* __restrict__ Wk, const float* __restrict__ bk,
    const float* __restrict__ Wv, const float* __restrict__ bv,
    float* __restrict__ qT, float* __restrict__ kT, float* __restrict__ vT)
{
    __shared__ float Ws[3 * 64 * 64];   // 48 KB
    __shared__ float xs[64 * 32];       // 8 KB
    const int t  = threadIdx.x;
    const int b  = blockIdx.x >> 7;          // 128 tiles of 32 voxels per batch
    const int i0 = (blockIdx.x & 127) * 32;

    // stage all three W (3 x 4096 floats), coalesced float4
    {
        const float4* Wq4 = (const float4*)Wq;
        const float4* Wk4 = (const float4*)Wk;
        const float4* Wv4 = (const float4*)Wv;
        float4* Ws4 = (float4*)Ws;
#pragma unroll
        for (int s = 0; s < 4; ++s) {
            int idx = t + 256 * s;           // 0..1023
            Ws4[idx]        = Wq4[idx];
            Ws4[1024 + idx] = Wk4[idx];
            Ws4[2048 + idx] = Wv4[idx];
        }
    }
    // stage x tile: xs[cc][m] = x[b][cc][i0+m], m in [0,32)
    {
        int cc = t >> 2;
        int m0 = (t & 3) * 8;
        const float* src = x + ((b * CCH + cc) * NVOX) + i0 + m0;
#pragma unroll
        for (int s = 0; s < 8; ++s) xs[cc * 32 + m0 + s] = src[s];
    }
    __syncthreads();

    const int vox = t & 31;
    const int c0  = (t >> 5) * 8;

#pragma unroll
    for (int m = 0; m < 3; ++m) {
        const float* Wm  = &Ws[m * 4096];
        const float* bia = (m == 0) ? bq : (m == 1) ? bk : bv;
        float* dst = ((m == 0) ? qT : (m == 1) ? kT : vT)
                     + ((b * NVOX) + i0 + vox) * CCH + c0;
        float acc[8];
#pragma unroll
        for (int j = 0; j < 8; ++j) acc[j] = bia[c0 + j];
        for (int cc = 0; cc < 64; cc += 4) {
            float xv0 = xs[(cc + 0) * 32 + vox];
            float xv1 = xs[(cc + 1) * 32 + vox];
            float xv2 = xs[(cc + 2) * 32 + vox];
            float xv3 = xs[(cc + 3) * 32 + vox];
#pragma unroll
            for (int j = 0; j < 8; ++j) {
                float4 w = *(const float4*)&Wm[(c0 + j) * 64 + cc];
                acc[j] = fmaf(w.x, xv0, acc[j]);
                acc[j] = fmaf(w.y, xv1, acc[j]);
                acc[j] = fmaf(w.z, xv2, acc[j]);
                acc[j] = fmaf(w.w, xv3, acc[j]);
            }
        }
        *(float4*)(dst)     = make_float4(acc[0], acc[1], acc[2], acc[3]);
        *(float4*)(dst + 4) = make_float4(acc[4], acc[5], acc[6], acc[7]);
    }
}

// ---------------- Kernel B: flash attention ----------------
// Each block: one 64-row i-tile, 1/SPLIT of the j range, online softmax.
// SPLIT==2: write unnormalized partials (po, ml) -> combine kernel.
// SPLIT==1: write final normalized output directly.
template <int SPLIT>
__global__ __launch_bounds__(256) void attn(
    const float* __restrict__ qT, const float* __restrict__ kT,
    const float* __restrict__ vT,
    float* __restrict__ po,   // [B*N][2][64]
    float* __restrict__ ml,   // [B*N][2][2]
    float* __restrict__ out)  // [B][C][N]
{
    __shared__ float qsT[64 * 64]; // [cc][i]
    __shared__ float ksT[64 * 64]; // [cc][j]
    __shared__ float vs [64 * 64]; // [j][c]
    __shared__ float psT[64 * 64]; // [j][i]

    const int t    = threadIdx.x;
    const int h    = (SPLIT == 2) ? (blockIdx.x & 1) : 0;
    const int tile = (SPLIT == 2) ? (blockIdx.x >> 1) : blockIdx.x;
    const int b    = tile >> 6;
    const int i0   = (tile & 63) * 64;
    const int tx   = t & 15, ty = t >> 4;

    // stage Q transposed: qsT[cc][i] = qT[b][i0+i][cc]
    {
        int ii = t >> 2;
        int c0 = (t & 3) * 16;
        const float* src = qT + ((b * NVOX) + i0 + ii) * CCH + c0;
#pragma unroll
        for (int s0 = 0; s0 < 16; s0 += 4) {
            float4 v = *(const float4*)(src + s0);
            qsT[(c0 + s0 + 0) * 64 + ii] = v.x;
            qsT[(c0 + s0 + 1) * 64 + ii] = v.y;
            qsT[(c0 + s0 + 2) * 64 + ii] = v.z;
            qsT[(c0 + s0 + 3) * 64 + ii] = v.w;
        }
    }

    float m_prev[4], l[4], o[4][4];
#pragma unroll
    for (int a = 0; a < 4; ++a) {
        m_prev[a] = -1e30f; l[a] = 0.f;
#pragma unroll
        for (int bb = 0; bb < 4; ++bb) o[a][bb] = 0.f;
    }

    const int JT = 64 / SPLIT;
    for (int jt = 0; jt < JT; ++jt) {
        const int j0 = h * (NVOX / 2) + jt * 64;
        __syncthreads();
        // stage ksT (transposed) and vs
        {
            int jj = t >> 2;
            int c0 = (t & 3) * 16;
            const float* ksrc = kT + ((b * NVOX) + j0 + jj) * CCH + c0;
            const float* vsrc = vT + ((b * NVOX) + j0 + jj) * CCH + c0;
#pragma unroll
            for (int s0 = 0; s0 < 16; s0 += 4) {
                float4 kv = *(const float4*)(ksrc + s0);
                ksT[(c0 + s0 + 0) * 64 + jj] = kv.x;
                ksT[(c0 + s0 + 1) * 64 + jj] = kv.y;
                ksT[(c0 + s0 + 2) * 64 + jj] = kv.z;
                ksT[(c0 + s0 + 3) * 64 + jj] = kv.w;
                *(float4*)&vs[jj * 64 + c0 + s0] = *(const float4*)(vsrc + s0);
            }
        }
        __syncthreads();

        // S = Q K^T, 4x4 register tile per thread: i = 4*ty+a, j = 4*tx+bb
        float s[4][4];
#pragma unroll
        for (int a = 0; a < 4; ++a)
#pragma unroll
            for (int bb = 0; bb < 4; ++bb) s[a][bb] = 0.f;
#pragma unroll 4
        for (int cc = 0; cc < 64; ++cc) {
            float4 qv = *(const float4*)&qsT[cc * 64 + ty * 4];
            float4 kv = *(const float4*)&ksT[cc * 64 + tx * 4];
            float qa[4] = {qv.x, qv.y, qv.z, qv.w};
            float ka[4] = {kv.x, kv.y, kv.z, kv.w};
#pragma unroll
            for (int a = 0; a < 4; ++a)
#pragma unroll
                for (int bb = 0; bb < 4; ++bb)
                    s[a][bb] = fmaf(qa[a], ka[bb], s[a][bb]);
        }

        // online softmax; row i = 4*ty+a is held by the 16 lanes sharing ty
        float p[4][4], alpha[4];
#pragma unroll
        for (int a = 0; a < 4; ++a) {
            float mx = fmaxf(fmaxf(s[a][0], s[a][1]), fmaxf(s[a][2], s[a][3]));
#pragma unroll
            for (int off = 1; off < 16; off <<= 1)
                mx = fmaxf(mx, __shfl_xor(mx, off, 64));
            float m_new = fmaxf(m_prev[a], mx);
            float sum = 0.f;
#pragma unroll
            for (int bb = 0; bb < 4; ++bb) {
                p[a][bb] = __expf(s[a][bb] - m_new);
                sum += p[a][bb];
            }
#pragma unroll
            for (int off = 1; off < 16; off <<= 1)
                sum += __shfl_xor(sum, off, 64);
            alpha[a]  = __expf(m_prev[a] - m_new);
            l[a]      = l[a] * alpha[a] + sum;
            m_prev[a] = m_new;
        }

        // write P^T to LDS: psT[j][i]
#pragma unroll
        for (int bb = 0; bb < 4; ++bb)
            *(float4*)&psT[(tx * 4 + bb) * 64 + ty * 4] =
                make_float4(p[0][bb], p[1][bb], p[2][bb], p[3][bb]);
        __syncthreads();

        // O = O*alpha + P V ; O[i][c], i = 4*ty+a, c = 4*tx+bb
#pragma unroll
        for (int a = 0; a < 4; ++a)
#pragma unroll
            for (int bb = 0; bb < 4; ++bb) o[a][bb] *= alpha[a];
#pragma unroll 4
        for (int j = 0; j < 64; ++j) {
            float4 pv = *(const float4*)&psT[j * 64 + ty * 4];
            float4 vv = *(const float4*)&vs[j * 64 + tx * 4];
            float pa[4] = {pv.x, pv.y, pv.z, pv.w};
            float va[4] = {vv.x, vv.y, vv.z, vv.w};
#pragma unroll
            for (int a = 0; a < 4; ++a)
#pragma unroll
                for (int bb = 0; bb < 4; ++bb)
                    o[a][bb] = fmaf(pa[a], va[bb], o[a][bb]);
        }
    }

    if (SPLIT == 2) {
#pragma unroll
        for (int a = 0; a < 4; ++a) {
            int row = b * NVOX + i0 + ty * 4 + a;
            *(float4*)&po[(row * 2 + h) * 64 + tx * 4] =
                make_float4(o[a][0], o[a][1], o[a][2], o[a][3]);
            if (tx == 0) {
                ml[(row * 2 + h) * 2 + 0] = m_prev[a];
                ml[(row * 2 + h) * 2 + 1] = l[a];
            }
        }
    } else {
        float inv[4];
#pragma unroll
        for (int a = 0; a < 4; ++a) inv[a] = 1.0f / l[a];
#pragma unroll
        for (int bb = 0; bb < 4; ++bb) {
            int c = tx * 4 + bb;
            *(float4*)&out[(b * CCH + c) * NVOX + i0 + ty * 4] =
                make_float4(o[0][bb] * inv[0], o[1][bb] * inv[1],
                            o[2][bb] * inv[2], o[3][bb] * inv[3]);
        }
    }
}

// ---------------- Kernel C: combine the two j-halves ----------------
__global__ __launch_bounds__(256) void combine(
    const float* __restrict__ po, const float* __restrict__ ml,
    float* __restrict__ out)
{
    const int t   = threadIdx.x;
    const int row = blockIdx.x * 64 + (t >> 2);   // 0..B*N-1
    const int c0  = (t & 3) * 16;
    const float m0 = ml[row * 4 + 0], l0 = ml[row * 4 + 1];
    const float m1 = ml[row * 4 + 2], l1 = ml[row * 4 + 3];
    const float M  = fmaxf(m0, m1);
    const float a0 = __expf(m0 - M), a1 = __expf(m1 - M);
    const float inv = 1.0f / (l0 * a0 + l1 * a1);
    const int b = row >> 12;
    const int i = row & 4095;
#pragma unroll
    for (int s = 0; s < 16; ++s) {
        int c = c0 + s;
        float v = (po[row * 128 + c] * a0 + po[row * 128 + 64 + c] * a1) * inv;
        out[(b * CCH + c) * NVOX + i] = v;
    }
}

extern "C" void kernel_launch(void* const* d_in, const int* in_sizes, int n_in,
                              void* d_out, int out_size, void* d_ws, size_t ws_size,
                              hipStream_t stream)
{
    const float* x  = (const float*)d_in[0];
    const float* Wq = (const float*)d_in[1];
    const float* bq = (const float*)d_in[2];
    const float* Wk = (const float*)d_in[3];
    const float* bk = (const float*)d_in[4];
    const float* Wv = (const float*)d_in[5];
    const float* bv = (const float*)d_in[6];
    float* out = (float*)d_out;
    float* ws  = (float*)d_ws;

    float* qT = ws;                          // B*N*C floats
    float* kT = qT + NB * NVOX * CCH;
    float* vT = kT + NB * NVOX * CCH;
    float* po = vT + NB * NVOX * CCH;        // B*N*2*64 floats
    float* ml = po + NB * NVOX * 2 * CCH;    // B*N*2*2 floats

    const size_t need_split2 =
        (size_t)(3 * NB * NVOX * CCH + NB * NVOX * 2 * CCH + NB * NVOX * 4) * sizeof(float);

    qkv_proj<<<NB * (NVOX / 32), 256, 0, stream>>>(x, Wq, bq, Wk, bk, Wv, bv, qT, kT, vT);

    if (ws_size >= need_split2) {
        attn<2><<<NB * (NVOX / 64) * 2, 256, 0, stream>>>(qT, kT, vT, po, ml, out);
        combine<<<(NB * NVOX) / 64, 256, 0, stream>>>(po, ml, out);
    } else {
        attn<1><<<NB * (NVOX / 64), 256, 0, stream>>>(qT, kT, vT, po, ml, out);
    }
}

// Round 2
// 118.038 us; speedup vs baseline: 2.3159x; 2.3159x over previous
//
#include <hip/hip_runtime.h>
#include <math.h>

#define CCH 64
#define NVOX 4096
#define NB 2
#define RS 72   // padded LDS row stride in halves (64 data + 8 pad = 144 B)

typedef _Float16 f16x8 __attribute__((ext_vector_type(8)));
typedef float f32x4 __attribute__((ext_vector_type(4)));

// ---------------- Kernel A: fused QKV projection ----------------
// x: [B, C, N] fp32; W*: [C, C] (out, in); b*: [C]
// qh, kh: [B, N, C] f16 ; vh: [B, C, N] f16
__global__ __launch_bounds__(256) void qkv_proj(
    const float* __restrict__ x,
    const float* __restrict__ Wq, const float* __restrict__ bq,
    const float* __restrict__ Wk, const float* __restrict__ bk,
    const float* __restrict__ Wv, const float* __restrict__ bv,
    _Float16* __restrict__ qh, _Float16* __restrict__ kh, _Float16* __restrict__ vh)
{
    __shared__ float Ws[3 * 64 * 64];   // 48 KB
    __shared__ float xs[64 * 32];       // 8 KB
    const int t  = threadIdx.x;
    const int b  = blockIdx.x >> 7;          // 128 tiles of 32 voxels per batch
    const int i0 = (blockIdx.x & 127) * 32;

    {
        const float4* Wq4 = (const float4*)Wq;
        const float4* Wk4 = (const float4*)Wk;
        const float4* Wv4 = (const float4*)Wv;
        float4* Ws4 = (float4*)Ws;
#pragma unroll
        for (int s = 0; s < 4; ++s) {
            int idx = t + 256 * s;
            Ws4[idx]        = Wq4[idx];
            Ws4[1024 + idx] = Wk4[idx];
            Ws4[2048 + idx] = Wv4[idx];
        }
    }
    {
        int cc = t >> 2;
        int m0 = (t & 3) * 8;
        const float* src = x + ((b * CCH + cc) * NVOX) + i0 + m0;
#pragma unroll
        for (int s = 0; s < 8; ++s) xs[cc * 32 + m0 + s] = src[s];
    }
    __syncthreads();

    const int vox = t & 31;
    const int c0  = (t >> 5) * 8;

#pragma unroll
    for (int m = 0; m < 3; ++m) {
        const float* Wm  = &Ws[m * 4096];
        const float* bia = (m == 0) ? bq : (m == 1) ? bk : bv;
        float acc[8];
#pragma unroll
        for (int j = 0; j < 8; ++j) acc[j] = bia[c0 + j];
        for (int cc = 0; cc < 64; cc += 4) {
            float xv0 = xs[(cc + 0) * 32 + vox];
            float xv1 = xs[(cc + 1) * 32 + vox];
            float xv2 = xs[(cc + 2) * 32 + vox];
            float xv3 = xs[(cc + 3) * 32 + vox];
#pragma unroll
            for (int j = 0; j < 8; ++j) {
                float4 w = *(const float4*)&Wm[(c0 + j) * 64 + cc];
                acc[j] = fmaf(w.x, xv0, acc[j]);
                acc[j] = fmaf(w.y, xv1, acc[j]);
                acc[j] = fmaf(w.z, xv2, acc[j]);
                acc[j] = fmaf(w.w, xv3, acc[j]);
            }
        }
        if (m < 2) {
            f16x8 hv;
#pragma unroll
            for (int j = 0; j < 8; ++j) hv[j] = (_Float16)acc[j];
            _Float16* dst = ((m == 0) ? qh : kh) + ((b * NVOX) + i0 + vox) * CCH + c0;
            *(f16x8*)dst = hv;
        } else {
#pragma unroll
            for (int j = 0; j < 8; ++j)
                vh[(b * CCH + c0 + j) * NVOX + i0 + vox] = (_Float16)acc[j];
        }
    }
}

// ---------------- Kernel B: MFMA flash attention ----------------
// Per block: 64-row i-tile (4 waves x 16 rows), 1/SPLIT of j range.
// S = Q K^T via mfma_f32_16x16x32_f16 (A=Q [i][c], B=K^T from ks[j][c]).
// O^T = V^T P^T (A=V^T from vsl[c][j], B=P^T from per-wave ps[i][j]).
template <int SPLIT>
__global__ __launch_bounds__(256) void attn(
    const _Float16* __restrict__ qh, const _Float16* __restrict__ kh,
    const _Float16* __restrict__ vh,
    float* __restrict__ po,   // [B*SPLIT][64][N] unnormalized O^T partials
    float* __restrict__ ml,   // [B*SPLIT][N][2] (m, l)
    float* __restrict__ out)  // [B][C][N]
{
    __shared__ _Float16 qs [64 * RS];      // [i][c]
    __shared__ _Float16 ksl[64 * RS];      // [j][c]
    __shared__ _Float16 vsl[64 * RS];      // [c][j]
    __shared__ _Float16 ps [4 * 16 * RS];  // per-wave [i 16][j 64]
    __shared__ float    als[4 * 16];       // per-wave alpha / inv-l broadcast

    constexpr int LS = (SPLIT == 4) ? 2 : (SPLIT == 2) ? 1 : 0;
    const int t    = threadIdx.x;
    const int h    = blockIdx.x & (SPLIT - 1);
    const int tile = blockIdx.x >> LS;
    const int b    = tile >> 6;
    const int i0   = (tile & 63) * 64;

    const int lane = t & 63;
    const int w    = t >> 6;         // wave id: rows [w*16, w*16+16)
    const int q4   = lane >> 4;      // quad id
    const int n    = lane & 15;

    // stage Q tile: qs[i][c], 32 B per thread
    {
        int row = t >> 2, c0 = (t & 3) * 16;
        const float4* src = (const float4*)&qh[((b * NVOX) + i0 + row) * CCH + c0];
        *(float4*)&qs[row * RS + c0]     = src[0];
        *(float4*)&qs[row * RS + c0 + 8] = src[1];
    }

    f16x8 aq[2];
    float m_prev[4], l[4];
    f32x4 o[4];
#pragma unroll
    for (int r = 0; r < 4; ++r) { m_prev[r] = -1e30f; l[r] = 0.f; }
#pragma unroll
    for (int mt = 0; mt < 4; ++mt) o[mt] = (f32x4){0.f, 0.f, 0.f, 0.f};

    const int JT = 64 / SPLIT;
    for (int jt = 0; jt < JT; ++jt) {
        const int j0 = (h * JT + jt) * 64;
        __syncthreads();   // protect prior iteration's ksl/vsl/ps reads (and qs staging on jt==0)
        {
            int row = t >> 2, c0 = (t & 3) * 16;
            const float4* ks = (const float4*)&kh[((b * NVOX) + j0 + row) * CCH + c0];
            *(float4*)&ksl[row * RS + c0]     = ks[0];
            *(float4*)&ksl[row * RS + c0 + 8] = ks[1];
            const float4* vs = (const float4*)&vh[(b * CCH + row) * NVOX + j0 + c0];
            *(float4*)&vsl[row * RS + c0]     = vs[0];
            *(float4*)&vsl[row * RS + c0 + 8] = vs[1];
        }
        __syncthreads();

        if (jt == 0) {
#pragma unroll
            for (int ks = 0; ks < 2; ++ks)
                aq[ks] = *(const f16x8*)&qs[(w * 16 + n) * RS + ks * 32 + q4 * 8];
        }

        // S = Q K^T : 4 n-tiles (16 j each) x 2 k-steps
        f32x4 s[4];
#pragma unroll
        for (int nt = 0; nt < 4; ++nt) s[nt] = (f32x4){0.f, 0.f, 0.f, 0.f};
#pragma unroll
        for (int ks = 0; ks < 2; ++ks) {
#pragma unroll
            for (int nt = 0; nt < 4; ++nt) {
                f16x8 bk = *(const f16x8*)&ksl[(nt * 16 + n) * RS + ks * 32 + q4 * 8];
                s[nt] = __builtin_amdgcn_mfma_f32_16x16x32_f16(aq[ks], bk, s[nt], 0, 0, 0);
            }
        }

        // online softmax; lane holds rows i_loc = q4*4 + r, cols j = nt*16 + n
        float p[4][4], alpha[4];
#pragma unroll
        for (int r = 0; r < 4; ++r) {
            float mx = fmaxf(fmaxf(s[0][r], s[1][r]), fmaxf(s[2][r], s[3][r]));
#pragma unroll
            for (int off = 1; off < 16; off <<= 1)
                mx = fmaxf(mx, __shfl_xor(mx, off, 64));
            float mn = fmaxf(m_prev[r], mx);
            float sum = 0.f;
#pragma unroll
            for (int nt = 0; nt < 4; ++nt) {
                p[nt][r] = __expf(s[nt][r] - mn);
                sum += p[nt][r];
            }
#pragma unroll
            for (int off = 1; off < 16; off <<= 1)
                sum += __shfl_xor(sum, off, 64);
            alpha[r]  = __expf(m_prev[r] - mn);
            l[r]      = l[r] * alpha[r] + sum;
            m_prev[r] = mn;
        }

        // P -> per-wave LDS in [i][j] layout (B-operand source for P^T)
#pragma unroll
        for (int nt = 0; nt < 4; ++nt)
#pragma unroll
            for (int r = 0; r < 4; ++r)
                ps[w * 16 * RS + (q4 * 4 + r) * RS + nt * 16 + n] = (_Float16)p[nt][r];
        if (n == 0)
            *(float4*)&als[w * 16 + q4 * 4] =
                make_float4(alpha[0], alpha[1], alpha[2], alpha[3]);
        __syncthreads();

        // O^T = V^T P^T ; rescale O^T by alpha[i = lane&15] first
        float a_i = als[w * 16 + n];
#pragma unroll
        for (int mt = 0; mt < 4; ++mt)
#pragma unroll
            for (int r = 0; r < 4; ++r) o[mt][r] *= a_i;

        f16x8 bp[2];
#pragma unroll
        for (int ks = 0; ks < 2; ++ks)
            bp[ks] = *(const f16x8*)&ps[w * 16 * RS + n * RS + ks * 32 + q4 * 8];
#pragma unroll
        for (int mt = 0; mt < 4; ++mt) {
#pragma unroll
            for (int ks = 0; ks < 2; ++ks) {
                f16x8 av = *(const f16x8*)&vsl[(mt * 16 + n) * RS + ks * 32 + q4 * 8];
                o[mt] = __builtin_amdgcn_mfma_f32_16x16x32_f16(av, bp[ks], o[mt], 0, 0, 0);
            }
        }
    }

    const int ig = i0 + w * 16 + n;   // global i this lane holds (O^T col)
    if (SPLIT > 1) {
        const size_t base = ((size_t)(b * SPLIT + h) * 64) * NVOX;
#pragma unroll
        for (int mt = 0; mt < 4; ++mt)
#pragma unroll
            for (int r = 0; r < 4; ++r)
                po[base + (size_t)(mt * 16 + q4 * 4 + r) * NVOX + ig] = o[mt][r];
        if (n == 0) {
            const int mlbase = ((b * SPLIT + h) * NVOX + i0 + w * 16 + q4 * 4) * 2;
            *(float4*)&ml[mlbase]     = make_float4(m_prev[0], l[0], m_prev[1], l[1]);
            *(float4*)&ml[mlbase + 4] = make_float4(m_prev[2], l[2], m_prev[3], l[3]);
        }
    } else {
        if (n == 0)
            *(float4*)&als[w * 16 + q4 * 4] =
                make_float4(1.f / l[0], 1.f / l[1], 1.f / l[2], 1.f / l[3]);
        __syncthreads();
        float inv = als[w * 16 + n];
#pragma unroll
        for (int mt = 0; mt < 4; ++mt)
#pragma unroll
            for (int r = 0; r < 4; ++r)
                out[(size_t)(b * CCH + mt * 16 + q4 * 4 + r) * NVOX + ig] = o[mt][r] * inv;
    }
}

// ---------------- Kernel C: combine split-j partials ----------------
template <int SPLIT>
__global__ __launch_bounds__(256) void combine(
    const float* __restrict__ po, const float* __restrict__ ml,
    float* __restrict__ out)
{
    __shared__ float wls[SPLIT * 64];
    const int t  = threadIdx.x;
    const int b  = blockIdx.x >> 6;
    const int i0 = (blockIdx.x & 63) * 64;

    if (t < 64) {
        const int i = i0 + t;
        float mv[SPLIT], lv[SPLIT], M = -1e30f;
#pragma unroll
        for (int h = 0; h < SPLIT; ++h) {
            mv[h] = ml[((b * SPLIT + h) * NVOX + i) * 2 + 0];
            lv[h] = ml[((b * SPLIT + h) * NVOX + i) * 2 + 1];
            M = fmaxf(M, mv[h]);
        }
        float den = 0.f;
#pragma unroll
        for (int h = 0; h < SPLIT; ++h) den += lv[h] * __expf(mv[h] - M);
        const float inv = 1.0f / den;
#pragma unroll
        for (int h = 0; h < SPLIT; ++h) wls[h * 64 + t] = __expf(mv[h] - M) * inv;
    }
    __syncthreads();

    const int c  = t >> 2;
    const int iq = t & 3;
    float4 acc[4];
#pragma unroll
    for (int u = 0; u < 4; ++u) acc[u] = make_float4(0.f, 0.f, 0.f, 0.f);
#pragma unroll
    for (int h = 0; h < SPLIT; ++h) {
        const float4* src = (const float4*)&po[((size_t)(b * SPLIT + h) * 64 + c) * NVOX + i0 + iq * 16];
        const float*  wp  = &wls[h * 64 + iq * 16];
#pragma unroll
        for (int u = 0; u < 4; ++u) {
            float4 f = src[u];
            float4 wv = *(const float4*)&wp[u * 4];
            acc[u].x = fmaf(f.x, wv.x, acc[u].x);
            acc[u].y = fmaf(f.y, wv.y, acc[u].y);
            acc[u].z = fmaf(f.z, wv.z, acc[u].z);
            acc[u].w = fmaf(f.w, wv.w, acc[u].w);
        }
    }
    float4* dst = (float4*)&out[(size_t)(b * CCH + c) * NVOX + i0 + iq * 16];
#pragma unroll
    for (int u = 0; u < 4; ++u) dst[u] = acc[u];
}

extern "C" void kernel_launch(void* const* d_in, const int* in_sizes, int n_in,
                              void* d_out, int out_size, void* d_ws, size_t ws_size,
                              hipStream_t stream)
{
    const float* x  = (const float*)d_in[0];
    const float* Wq = (const float*)d_in[1];
    const float* bq = (const float*)d_in[2];
    const float* Wk = (const float*)d_in[3];
    const float* bk = (const float*)d_in[4];
    const float* Wv = (const float*)d_in[5];
    const float* bv = (const float*)d_in[6];
    float* out = (float*)d_out;

    _Float16* qh = (_Float16*)d_ws;                 // B*N*C halves
    _Float16* kh = qh + NB * NVOX * CCH;
    _Float16* vh = kh + NB * NVOX * CCH;
    float*    po = (float*)(vh + NB * NVOX * CCH);  // B*SPLIT*64*N floats
    const size_t qkv_bytes = (size_t)3 * NB * NVOX * CCH * sizeof(_Float16);

    qkv_proj<<<NB * (NVOX / 32), 256, 0, stream>>>(x, Wq, bq, Wk, bk, Wv, bv, qh, kh, vh);

    const size_t need4 = qkv_bytes + (size_t)NB * 4 * (64 + 2) * NVOX * sizeof(float);
    const size_t need2 = qkv_bytes + (size_t)NB * 2 * (64 + 2) * NVOX * sizeof(float);

    if (ws_size >= need4) {
        float* ml = po + (size_t)NB * 4 * 64 * NVOX;
        attn<4><<<NB * 64 * 4, 256, 0, stream>>>(qh, kh, vh, po, ml, out);
        combine<4><<<NB * 64, 256, 0, stream>>>(po, ml, out);
    } else if (ws_size >= need2) {
        float* ml = po + (size_t)NB * 2 * 64 * NVOX;
        attn<2><<<NB * 64 * 2, 256, 0, stream>>>(qh, kh, vh, po, ml, out);
        combine<2><<<NB * 64, 256, 0, stream>>>(po, ml, out);
    } else {
        attn<1><<<NB * 64, 256, 0, stream>>>(qh, kh, vh, nullptr, nullptr, out);
    }
}

// Round 3
// 109.766 us; speedup vs baseline: 2.4904x; 1.0754x over previous
//
#include <hip/hip_runtime.h>
#include <math.h>

#define CCH 64
#define NVOX 4096
#define NB 2
#define RS 72   // padded LDS row stride in halves (64 data + 8 pad = 144 B)

typedef _Float16 f16x8 __attribute__((ext_vector_type(8)));
typedef _Float16 f16x4 __attribute__((ext_vector_type(4)));
typedef float f32x4 __attribute__((ext_vector_type(4)));

// ---------------- Kernel A: fused QKV projection ----------------
// x: [B, C, N] fp32; W*: [C, C] (out, in); b*: [C]
// qh, kh: [B, N, C] f16 ; vh: [B, C, N] f16
__global__ __launch_bounds__(256) void qkv_proj(
    const float* __restrict__ x,
    const float* __restrict__ Wq, const float* __restrict__ bq,
    const float* __restrict__ Wk, const float* __restrict__ bk,
    const float* __restrict__ Wv, const float* __restrict__ bv,
    _Float16* __restrict__ qh, _Float16* __restrict__ kh, _Float16* __restrict__ vh)
{
    __shared__ float Ws[3 * 64 * 64];   // 48 KB
    __shared__ float xs[64 * 32];       // 8 KB
    const int t  = threadIdx.x;
    const int b  = blockIdx.x >> 7;          // 128 tiles of 32 voxels per batch
    const int i0 = (blockIdx.x & 127) * 32;

    {
        const float4* Wq4 = (const float4*)Wq;
        const float4* Wk4 = (const float4*)Wk;
        const float4* Wv4 = (const float4*)Wv;
        float4* Ws4 = (float4*)Ws;
#pragma unroll
        for (int s = 0; s < 4; ++s) {
            int idx = t + 256 * s;
            Ws4[idx]        = Wq4[idx];
            Ws4[1024 + idx] = Wk4[idx];
            Ws4[2048 + idx] = Wv4[idx];
        }
    }
    {
        int cc = t >> 2;
        int m0 = (t & 3) * 8;
        const float* src = x + ((b * CCH + cc) * NVOX) + i0 + m0;
#pragma unroll
        for (int s = 0; s < 8; ++s) xs[cc * 32 + m0 + s] = src[s];
    }
    __syncthreads();

    const int vox = t & 31;
    const int c0  = (t >> 5) * 8;

#pragma unroll
    for (int m = 0; m < 3; ++m) {
        const float* Wm  = &Ws[m * 4096];
        const float* bia = (m == 0) ? bq : (m == 1) ? bk : bv;
        float acc[8];
#pragma unroll
        for (int j = 0; j < 8; ++j) acc[j] = bia[c0 + j];
        for (int cc = 0; cc < 64; cc += 4) {
            float xv0 = xs[(cc + 0) * 32 + vox];
            float xv1 = xs[(cc + 1) * 32 + vox];
            float xv2 = xs[(cc + 2) * 32 + vox];
            float xv3 = xs[(cc + 3) * 32 + vox];
#pragma unroll
            for (int j = 0; j < 8; ++j) {
                float4 w = *(const float4*)&Wm[(c0 + j) * 64 + cc];
                acc[j] = fmaf(w.x, xv0, acc[j]);
                acc[j] = fmaf(w.y, xv1, acc[j]);
                acc[j] = fmaf(w.z, xv2, acc[j]);
                acc[j] = fmaf(w.w, xv3, acc[j]);
            }
        }
        if (m < 2) {
            f16x8 hv;
#pragma unroll
            for (int j = 0; j < 8; ++j) hv[j] = (_Float16)acc[j];
            _Float16* dst = ((m == 0) ? qh : kh) + ((b * NVOX) + i0 + vox) * CCH + c0;
            *(f16x8*)dst = hv;
        } else {
#pragma unroll
            for (int j = 0; j < 8; ++j)
                vh[(b * CCH + c0 + j) * NVOX + i0 + vox] = (_Float16)acc[j];
        }
    }
}

// ---------------- Kernel B: MFMA flash attention (S^T formulation) ----------------
// Per block: 64-row i-tile (4 waves x 16 rows), 1/SPLIT of j range.
// S^T = K Q^T via mfma_f32_16x16x32_f16: lane holds 16 scores of ONE row i=lane&15.
// Softmax: in-thread + 2 cross-quad shuffles; alpha per-lane (no LDS).
// O^T = V^T P^T via mfma_f32_16x16x16_f16: P^T B-frag comes straight from registers.
template <int SPLIT>
__global__ __launch_bounds__(256) void attn(
    const _Float16* __restrict__ qh, const _Float16* __restrict__ kh,
    const _Float16* __restrict__ vh,
    float* __restrict__ po,   // [B*SPLIT][64][N] unnormalized O^T partials
    float* __restrict__ ml,   // [B*SPLIT][N][2] (m, l)
    float* __restrict__ out)  // [B][C][N]
{
    __shared__ _Float16 ksl[64 * RS];      // [j][c]
    __shared__ _Float16 vsl[64 * RS];      // [c][j]

    constexpr int LS = (SPLIT == 8) ? 3 : (SPLIT == 4) ? 2 : (SPLIT == 2) ? 1 : 0;
    const int t    = threadIdx.x;
    const int h    = blockIdx.x & (SPLIT - 1);
    const int tile = blockIdx.x >> LS;
    const int b    = tile >> 6;
    const int i0   = (tile & 63) * 64;

    const int lane = t & 63;
    const int w    = t >> 6;         // wave id: rows [w*16, w*16+16)
    const int q4   = lane >> 4;      // quad id
    const int n    = lane & 15;      // this lane's row: i = i0 + w*16 + n

    // Q B-operand fragments, straight from global (one 16B + one 16B load)
    f16x8 aq[2];
    {
        const _Float16* qrow = qh + ((size_t)(b * NVOX) + i0 + w * 16 + n) * CCH + q4 * 8;
        aq[0] = *(const f16x8*)(qrow);
        aq[1] = *(const f16x8*)(qrow + 32);
    }

    float m_prev = -1e30f, l = 0.f;
    f32x4 o[4];
#pragma unroll
    for (int mt = 0; mt < 4; ++mt) o[mt] = (f32x4){0.f, 0.f, 0.f, 0.f};

    const int JT = 64 / SPLIT;
    for (int jt = 0; jt < JT; ++jt) {
        const int j0 = (h * JT + jt) * 64;
        __syncthreads();   // protect previous iteration's ksl/vsl reads
        {
            int row = t >> 2, c0 = (t & 3) * 16;
            const float4* ks = (const float4*)&kh[((size_t)(b * NVOX) + j0 + row) * CCH + c0];
            *(float4*)&ksl[row * RS + c0]     = ks[0];
            *(float4*)&ksl[row * RS + c0 + 8] = ks[1];
            const float4* vs = (const float4*)&vh[((size_t)b * CCH + row) * NVOX + j0 + c0];
            *(float4*)&vsl[row * RS + c0]     = vs[0];
            *(float4*)&vsl[row * RS + c0 + 8] = vs[1];
        }
        __syncthreads();

        // S^T = K Q^T : s[nt][r] = S[i = i0+w*16+n][j = j0 + nt*16 + q4*4 + r]
        f32x4 s[4];
#pragma unroll
        for (int nt = 0; nt < 4; ++nt) s[nt] = (f32x4){0.f, 0.f, 0.f, 0.f};
#pragma unroll
        for (int ks = 0; ks < 2; ++ks) {
#pragma unroll
            for (int nt = 0; nt < 4; ++nt) {
                f16x8 ak = *(const f16x8*)&ksl[(nt * 16 + n) * RS + ks * 32 + q4 * 8];
                s[nt] = __builtin_amdgcn_mfma_f32_16x16x32_f16(ak, aq[ks], s[nt], 0, 0, 0);
            }
        }

        // per-lane online softmax (all 16 values belong to row i = n)
        float mx = -1e30f;
#pragma unroll
        for (int nt = 0; nt < 4; ++nt)
#pragma unroll
            for (int r = 0; r < 4; ++r) mx = fmaxf(mx, s[nt][r]);
        mx = fmaxf(mx, __shfl_xor(mx, 16, 64));
        mx = fmaxf(mx, __shfl_xor(mx, 32, 64));
        const float mn = fmaxf(m_prev, mx);

        float p[4][4], sum = 0.f;
#pragma unroll
        for (int nt = 0; nt < 4; ++nt)
#pragma unroll
            for (int r = 0; r < 4; ++r) {
                p[nt][r] = __expf(s[nt][r] - mn);
                sum += p[nt][r];
            }
        sum += __shfl_xor(sum, 16, 64);
        sum += __shfl_xor(sum, 32, 64);

        const float alpha = __expf(m_prev - mn);
        l = l * alpha + sum;
        m_prev = mn;

        // rescale O^T (col = i = lane&15 -> alpha is per-lane)
#pragma unroll
        for (int mt = 0; mt < 4; ++mt)
#pragma unroll
            for (int r = 0; r < 4; ++r) o[mt][r] *= alpha;

        // P^T B-fragments for K=16 MFMA, straight from registers
        f16x4 bp[4];
#pragma unroll
        for (int nt = 0; nt < 4; ++nt)
#pragma unroll
            for (int r = 0; r < 4; ++r) bp[nt][r] = (_Float16)p[nt][r];

        // O^T += V^T P^T : o[mt][r] = O^T[c = mt*16 + q4*4 + r][i = n]
#pragma unroll
        for (int nt = 0; nt < 4; ++nt) {
#pragma unroll
            for (int mt = 0; mt < 4; ++mt) {
                f16x4 av = *(const f16x4*)&vsl[(mt * 16 + n) * RS + nt * 16 + q4 * 4];
                o[mt] = __builtin_amdgcn_mfma_f32_16x16x16f16(av, bp[nt], o[mt], 0, 0, 0);
            }
        }
    }

    const int ig = i0 + w * 16 + n;   // global i this lane holds (O^T col)
    if (SPLIT > 1) {
        const size_t base = ((size_t)(b * SPLIT + h) * 64) * NVOX;
#pragma unroll
        for (int mt = 0; mt < 4; ++mt)
#pragma unroll
            for (int r = 0; r < 4; ++r)
                po[base + (size_t)(mt * 16 + q4 * 4 + r) * NVOX + ig] = o[mt][r];
        if (q4 == 0) {
            float2* mlp = (float2*)&ml[((size_t)(b * SPLIT + h) * NVOX + ig) * 2];
            *mlp = make_float2(m_prev, l);
        }
    } else {
        const float inv = 1.0f / l;
#pragma unroll
        for (int mt = 0; mt < 4; ++mt)
#pragma unroll
            for (int r = 0; r < 4; ++r)
                out[(size_t)(b * CCH + mt * 16 + q4 * 4 + r) * NVOX + ig] = o[mt][r] * inv;
    }
}

// ---------------- Kernel C: combine split-j partials ----------------
template <int SPLIT>
__global__ __launch_bounds__(256) void combine(
    const float* __restrict__ po, const float* __restrict__ ml,
    float* __restrict__ out)
{
    __shared__ float wls[SPLIT * 64];
    const int t  = threadIdx.x;
    const int b  = blockIdx.x >> 6;
    const int i0 = (blockIdx.x & 63) * 64;

    if (t < 64) {
        const int i = i0 + t;
        float mv[SPLIT], lv[SPLIT], M = -1e30f;
#pragma unroll
        for (int h = 0; h < SPLIT; ++h) {
            mv[h] = ml[((size_t)(b * SPLIT + h) * NVOX + i) * 2 + 0];
            lv[h] = ml[((size_t)(b * SPLIT + h) * NVOX + i) * 2 + 1];
            M = fmaxf(M, mv[h]);
        }
        float den = 0.f;
#pragma unroll
        for (int h = 0; h < SPLIT; ++h) den += lv[h] * __expf(mv[h] - M);
        const float inv = 1.0f / den;
#pragma unroll
        for (int h = 0; h < SPLIT; ++h) wls[h * 64 + t] = __expf(mv[h] - M) * inv;
    }
    __syncthreads();

    const int c  = t >> 2;
    const int iq = t & 3;
    float4 acc[4];
#pragma unroll
    for (int u = 0; u < 4; ++u) acc[u] = make_float4(0.f, 0.f, 0.f, 0.f);
#pragma unroll
    for (int h = 0; h < SPLIT; ++h) {
        const float4* src = (const float4*)&po[((size_t)(b * SPLIT + h) * 64 + c) * NVOX + i0 + iq * 16];
        const float*  wp  = &wls[h * 64 + iq * 16];
#pragma unroll
        for (int u = 0; u < 4; ++u) {
            float4 f = src[u];
            float4 wv = *(const float4*)&wp[u * 4];
            acc[u].x = fmaf(f.x, wv.x, acc[u].x);
            acc[u].y = fmaf(f.y, wv.y, acc[u].y);
            acc[u].z = fmaf(f.z, wv.z, acc[u].z);
            acc[u].w = fmaf(f.w, wv.w, acc[u].w);
        }
    }
    float4* dst = (float4*)&out[(size_t)(b * CCH + c) * NVOX + i0 + iq * 16];
#pragma unroll
    for (int u = 0; u < 4; ++u) dst[u] = acc[u];
}

extern "C" void kernel_launch(void* const* d_in, const int* in_sizes, int n_in,
                              void* d_out, int out_size, void* d_ws, size_t ws_size,
                              hipStream_t stream)
{
    const float* x  = (const float*)d_in[0];
    const float* Wq = (const float*)d_in[1];
    const float* bq = (const float*)d_in[2];
    const float* Wk = (const float*)d_in[3];
    const float* bk = (const float*)d_in[4];
    const float* Wv = (const float*)d_in[5];
    const float* bv = (const float*)d_in[6];
    float* out = (float*)d_out;

    _Float16* qh = (_Float16*)d_ws;                 // B*N*C halves
    _Float16* kh = qh + NB * NVOX * CCH;
    _Float16* vh = kh + NB * NVOX * CCH;
    float*    po = (float*)(vh + NB * NVOX * CCH);  // B*SPLIT*64*N floats
    const size_t qkv_bytes = (size_t)3 * NB * NVOX * CCH * sizeof(_Float16);

    qkv_proj<<<NB * (NVOX / 32), 256, 0, stream>>>(x, Wq, bq, Wk, bk, Wv, bv, qh, kh, vh);

    const size_t need8 = qkv_bytes + (size_t)NB * 8 * (64 + 2) * NVOX * sizeof(float);
    const size_t need4 = qkv_bytes + (size_t)NB * 4 * (64 + 2) * NVOX * sizeof(float);
    const size_t need2 = qkv_bytes + (size_t)NB * 2 * (64 + 2) * NVOX * sizeof(float);

    if (ws_size >= need8) {
        float* ml = po + (size_t)NB * 8 * 64 * NVOX;
        attn<8><<<NB * 64 * 8, 256, 0, stream>>>(qh, kh, vh, po, ml, out);
        combine<8><<<NB * 64, 256, 0, stream>>>(po, ml, out);
    } else if (ws_size >= need4) {
        float* ml = po + (size_t)NB * 4 * 64 * NVOX;
        attn<4><<<NB * 64 * 4, 256, 0, stream>>>(qh, kh, vh, po, ml, out);
        combine<4><<<NB * 64, 256, 0, stream>>>(po, ml, out);
    } else if (ws_size >= need2) {
        float* ml = po + (size_t)NB * 2 * 64 * NVOX;
        attn<2><<<NB * 64 * 2, 256, 0, stream>>>(qh, kh, vh, po, ml, out);
        combine<2><<<NB * 64, 256, 0, stream>>>(po, ml, out);
    } else {
        attn<1><<<NB * 64, 256, 0, stream>>>(qh, kh, vh, nullptr, nullptr, out);
    }
}